// Round 8
// baseline (106.192 us; speedup 1.0000x reference)
//
#include <hip/hip_runtime.h>

// SPN forward, round 8: round-7 structure (16-col stages, 2-deep LDS ring,
// one lgkm-only barrier per interval) + FIX: double-buffered producer
// register blocks (RA/RB). Block k lives in buffer k&1; at iteration t the
// producer issues block t+2 into the just-freed buffer and norms block t+1
// from the other -- no register clobber (round-7 bug), FIFO-precise vmcnt,
// one-interval issue->use gap.

#define HD 256
#define WD 256
#define NS 16                   // 16-col stages
#define STG 260                 // padded column stride (floats)
#define ARR_F (16 * STG)        // one array, one stage (16 cols)
#define STAGE_F (4 * ARR_F)     // d, g1, g2, g3
#define TILE_OFF (2 * STAGE_F)  // out tile after the 2-deep ring

#define F4E(v, e) ((e) == 0 ? (v).x : (e) == 1 ? (v).y : (e) == 2 ? (v).z : (v).w)

#define FENCE_BAR()                                      \
  do {                                                   \
    asm volatile("s_waitcnt lgkmcnt(0)" ::: "memory");   \
    __builtin_amdgcn_s_barrier();                        \
    asm volatile("" ::: "memory");                       \
  } while (0)

__global__ __launch_bounds__(320, 1) void spn_fwd(
    const float* __restrict__ x, const float* __restrict__ G1,
    const float* __restrict__ G2, const float* __restrict__ G3,
    float* __restrict__ out)
{
  __shared__ float lds_f[2 * STAGE_F + 16 * STG];   // 149,760 B -> 1 block/CU

  const int tid = threadIdx.x;
  const int wid = tid >> 6;          // 0..3 producers, 4 consumer
  const int l   = tid & 63;
  const size_t pbase = (size_t)blockIdx.x * (HD * WD);
  const float* gp[4] = {x + pbase, G1 + pbase, G2 + pbase, G3 + pbase};
  float* op = out + pbase;

  if (wid < 4) {
    // ================= PRODUCER (rows 64*wid .. 64*wid+63) =================
    const int rq = l >> 2;           // row within 16-row group (0..15)
    const int cq = l & 3;            // col quad within 16-col stage (0..3)
    float4 RA[4][4], RB[4][4];       // two 16-col blocks in flight

    auto issueBlk = [&](float4 (&R)[4][4], int k) {
#pragma unroll
      for (int A = 0; A < 4; ++A)
#pragma unroll
        for (int i = 0; i < 4; ++i)
          R[A][i] = *(const float4*)(gp[A] +
              (size_t)(64 * wid + 16 * i + rq) * WD + 16 * k + 4 * cq);
    };

    auto normBlk = [&](float4 (&R)[4][4], int k) {
#pragma unroll
      for (int i = 0; i < 4; ++i) {
        const int row = 64 * wid + 16 * i + rq;
        const float uOk = (row > 0) ? 1.f : 0.f;
        const float dOk = (row < HD - 1) ? 1.f : 0.f;
        float nx[4], na[4], nb[4], nc[4];
#pragma unroll
        for (int e = 0; e < 4; ++e) {
          float a = F4E(R[1][i], e), b = F4E(R[2][i], e), c = F4E(R[3][i], e);
          float xx = F4E(R[0][i], e);
          float s = fabsf(a) + fabsf(b) + fabsf(c);
          float inv = (s >= 1.f) ? __builtin_amdgcn_rcpf(s) : 1.f;
          float cOk = (16 * k + 4 * cq + e > 0) ? 1.f : 0.f;  // global col 0
          float ga = a * inv * cOk * uOk;
          float gb = b * inv * cOk;
          float gc = c * inv * cOk * dOk;
          nx[e] = (1.f - ga - gb - gc) * xx;
          na[e] = ga; nb[e] = gb; nc[e] = gc;
        }
        R[0][i] = make_float4(nx[0], nx[1], nx[2], nx[3]);
        R[1][i] = make_float4(na[0], na[1], na[2], na[3]);
        R[2][i] = make_float4(nb[0], nb[1], nb[2], nb[3]);
        R[3][i] = make_float4(nc[0], nc[1], nc[2], nc[3]);
      }
    };

    auto writeStage = [&](float4 (&R)[4][4], float* dst) {
#pragma unroll
      for (int A = 0; A < 4; ++A)
#pragma unroll
        for (int i = 0; i < 4; ++i) {
          const int row = 64 * wid + 16 * i + rq;
#pragma unroll
          for (int e = 0; e < 4; ++e)
            dst[A * ARR_F + (4 * cq + e) * STG + row] = F4E(R[A][i], e);
        }
    };

    // prologue: blk0 -> RA -> stage 0 slot 0; blk1 -> RB in flight.
    issueBlk(RA, 0);
    normBlk(RA, 0);
    writeStage(RA, lds_f + 0 * STAGE_F);
    issueBlk(RB, 1);
    FENCE_BAR();

    // iteration t: issue blk t+2 into buffer t&1; norm+write blk t+1 from
    // buffer (t+1)&1 into slot (t+1)&1. 2x-unrolled -> static buffers.
#pragma unroll 1
    for (int tt = 0; tt < 8; ++tt) {
      const int t = 2 * tt;            // even
      if (t + 2 <= 15) issueBlk(RA, t + 2);
      if (t + 1 <= 15) {
        normBlk(RB, t + 1);            // waits only the older 16 loads
        writeStage(RB, lds_f + 1 * STAGE_F);
      }
      FENCE_BAR();
      const int u = t + 1;             // odd
      if (u + 2 <= 15) issueBlk(RB, u + 2);
      if (u + 1 <= 15) {
        normBlk(RA, u + 1);
        writeStage(RA, lds_f + 0 * STAGE_F);
      }
      FENCE_BAR();
    }
  } else {
    // ===================== CONSUMER (serial scan) =====================
    float h[4] = {0.f, 0.f, 0.f, 0.f};
    const int cb = 4 * (l & 3);
    const int rr = l >> 2;
    float* tile = lds_f + TILE_OFF;

    FENCE_BAR();   // matches producer prologue barrier

#pragma unroll 1
    for (int t = 0; t < NS; ++t) {
      const float* src = lds_f + (t & 1) * STAGE_F;
      float4 rd[2][4];                 // [phase][array], one column each

      // preload column 0
#pragma unroll
      for (int A = 0; A < 4; ++A)
        rd[0][A] = *(const float4*)(src + A * ARR_F + 0 * STG + 4 * l);

#pragma unroll
      for (int c = 0; c < 16; ++c) {
        const int cur = c & 1, nxt = cur ^ 1;
        if (c < 15) {
#pragma unroll
          for (int A = 0; A < 4; ++A)
            rd[nxt][A] = *(const float4*)(src + A * ARR_F + (c + 1) * STG + 4 * l);
        }
        const float shU = __shfl_up(h[3], 1);    // h[4l-1]
        const float shD = __shfl_down(h[0], 1);  // h[4l+4]
        float hn[4];
#pragma unroll
        for (int r = 0; r < 4; ++r) {
          float up = (r == 0) ? shU : h[r - 1];
          float dn = (r == 3) ? shD : h[r + 1];
          hn[r] = fmaf(F4E(rd[cur][1], r), up,
                  fmaf(F4E(rd[cur][2], r), h[r],
                  fmaf(F4E(rd[cur][3], r), dn, F4E(rd[cur][0], r))));
        }
#pragma unroll
        for (int r = 0; r < 4; ++r) h[r] = hn[r];
        *(float4*)(tile + c * STG + 4 * l) =
            make_float4(hn[0], hn[1], hn[2], hn[3]);
      }

      // gather rows -> full-64B-line coalesced stores (16 cols per stage)
#pragma unroll
      for (int kk = 0; kk < 16; ++kk) {
        const int row = 16 * kk + rr;
        float4 o;
        o.x = tile[(cb + 0) * STG + row];
        o.y = tile[(cb + 1) * STG + row];
        o.z = tile[(cb + 2) * STG + row];
        o.w = tile[(cb + 3) * STG + row];
        *(float4*)(op + (size_t)row * WD + 16 * t + cb) = o;
      }
      FENCE_BAR();
    }
  }
}

extern "C" void kernel_launch(void* const* d_in, const int* in_sizes, int n_in,
                              void* d_out, int out_size, void* d_ws, size_t ws_size,
                              hipStream_t stream) {
  const float* x  = (const float*)d_in[0];
  const float* g1 = (const float*)d_in[1];
  const float* g2 = (const float*)d_in[2];
  const float* g3 = (const float*)d_in[3];
  float* outp = (float*)d_out;
  const int planes = out_size / (HD * WD);   // B*C = 256
  spn_fwd<<<planes, 320, 0, stream>>>(x, g1, g2, g3, outp);
}